// Round 8
// baseline (129.801 us; speedup 1.0000x reference)
//
#include <hip/hip_runtime.h>

#define N 1024
#define DIM 128
#define TI 4      // rows per attn block
#define JCH 128   // j's per attn block
#define NCH 8     // number of j-chunks (N / JCH)
#define SC 16     // j sub-chunk per loop iter
#define NSC 8     // JCH / SC

// ---- DPP 32-lane sum (VALU pipe): group sums land in wave lanes 31 / 63 ----
template <int CTRL>
__device__ __forceinline__ float dpp_add(float x) {
  int y = __builtin_amdgcn_update_dpp(0, __float_as_int(x), CTRL, 0xF, 0xF, true);
  return x + __int_as_float(y);
}
__device__ __forceinline__ float red32(float x) {
  x = dpp_add<0x111>(x);  // row_shr:1
  x = dpp_add<0x112>(x);  // row_shr:2
  x = dpp_add<0x114>(x);  // row_shr:4
  x = dpp_add<0x118>(x);  // row_shr:8
  x = dpp_add<0x142>(x);  // row_bcast15 -> lanes 31/63 have their 32-lane sums
  return x;
}

// Broadcast the 32-lane group sum to every lane WITHOUT LDS.
__device__ __forceinline__ float bcast32(float x, bool hi) {
  const float a = __int_as_float(__builtin_amdgcn_readlane(__float_as_int(x), 31));
  const float b = __int_as_float(__builtin_amdgcn_readlane(__float_as_int(x), 63));
  return hi ? b : a;
}

__device__ __forceinline__ float epart(const float4 q, const float4 k,
                                       const float4 w) {
  float a = fmaxf(q.x + k.x, 0.f) * w.x;
  a = fmaf(fmaxf(q.y + k.y, 0.f), w.y, a);
  a = fmaf(fmaxf(q.z + k.z, 0.f), w.z, a);
  a = fmaf(fmaxf(q.w + k.w, 0.f), w.w, a);
  return a;
}

// ------------------------------------------------------------------
// Kernel 1: Q = x@W_Q+b_Q, K = x@W_K+b_K, V = x@W_V+b_V.  (r5-proven)
// ------------------------------------------------------------------
__global__ __launch_bounds__(256) void qkv_kernel2(
    const float* __restrict__ x,
    const float* __restrict__ WQ, const float* __restrict__ bQ,
    const float* __restrict__ WK, const float* __restrict__ bK,
    const float* __restrict__ WV, const float* __restrict__ bV,
    float* __restrict__ Q, float* __restrict__ K, float* __restrict__ V) {
  const int i0 = blockIdx.x * 2;
  const int t = threadIdx.x;
  const int dq = t & 31;
  const int g = t >> 5;
  const int r = g & 1;
  const int qr = g >> 1;

  __shared__ __align__(16) float xs[2][DIM];
  __shared__ __align__(16) float pacc[4][3][2][DIM];

  if (t < 64) {
    const int row = t >> 5, c4 = t & 31;
    ((float4*)&xs[row][0])[c4] = ((const float4*)(x + (i0 + row) * DIM))[c4];
  }
  __syncthreads();

  const float4* WQ4 = (const float4*)WQ;
  const float4* WK4 = (const float4*)WK;
  const float4* WV4 = (const float4*)WV;
  float4 aQ = make_float4(0.f, 0.f, 0.f, 0.f);
  float4 aK = make_float4(0.f, 0.f, 0.f, 0.f);
  float4 aV = make_float4(0.f, 0.f, 0.f, 0.f);
  const int cbase = 32 * qr;
  for (int cc = 0; cc < 32; ++cc) {
    const int c = cbase + cc;
    const float xv = xs[r][c];
    const float4 wq = WQ4[c * 32 + dq];
    const float4 wk = WK4[c * 32 + dq];
    const float4 wv = WV4[c * 32 + dq];
    aQ.x = fmaf(xv, wq.x, aQ.x); aQ.y = fmaf(xv, wq.y, aQ.y);
    aQ.z = fmaf(xv, wq.z, aQ.z); aQ.w = fmaf(xv, wq.w, aQ.w);
    aK.x = fmaf(xv, wk.x, aK.x); aK.y = fmaf(xv, wk.y, aK.y);
    aK.z = fmaf(xv, wk.z, aK.z); aK.w = fmaf(xv, wk.w, aK.w);
    aV.x = fmaf(xv, wv.x, aV.x); aV.y = fmaf(xv, wv.y, aV.y);
    aV.z = fmaf(xv, wv.z, aV.z); aV.w = fmaf(xv, wv.w, aV.w);
  }
  ((float4*)&pacc[qr][0][r][0])[dq] = aQ;
  ((float4*)&pacc[qr][1][r][0])[dq] = aK;
  ((float4*)&pacc[qr][2][r][0])[dq] = aV;
  __syncthreads();

  {
    const int row = t >> 7, d = t & 127;
    const float q = (pacc[0][0][row][d] + pacc[1][0][row][d]) +
                    (pacc[2][0][row][d] + pacc[3][0][row][d]) + bQ[d];
    const float k = (pacc[0][1][row][d] + pacc[1][1][row][d]) +
                    (pacc[2][1][row][d] + pacc[3][1][row][d]) + bK[d];
    const float v = (pacc[0][2][row][d] + pacc[1][2][row][d]) +
                    (pacc[2][2][row][d] + pacc[3][2][row][d]) + bV[d];
    Q[(i0 + row) * DIM + d] = q;
    K[(i0 + row) * DIM + d] = k;
    V[(i0 + row) * DIM + d] = v;
  }
}

// ------------------------------------------------------------------
// Kernel 2: barrier-free hot loop, zero LDS in the loop.  (r7-proven)
// ------------------------------------------------------------------
__global__ __launch_bounds__(256) void attn_fused4(
    const float* __restrict__ Q, const float* __restrict__ K,
    const float* __restrict__ V, const float* __restrict__ WA,
    float* __restrict__ Rw, float* __restrict__ Sw, float* __restrict__ Lw) {
  const int bi = blockIdx.x >> 3;
  const int jc = blockIdx.x & 7;
  const int i0 = bi * TI;
  const int j0 = jc * JCH;
  const int t = threadIdx.x;
  const int dq = t & 31;           // d-quad lane
  const int f = t >> 5;            // j-group 0..7
  const bool hi = (t & 32) != 0;   // which wave half this group occupies

  __shared__ __align__(16) float red_s[8 * TI * DIM];  // 16 KB epilogue buf
  __shared__ __align__(16) float4 lred4[8];

  const float4 wa4 = ((const float4*)WA)[dq];
  float4 q4[TI];
#pragma unroll
  for (int r = 0; r < TI; ++r)
    q4[r] = ((const float4*)(Q + (i0 + r) * DIM))[dq];

  float4 Racc[TI], Sacc[TI];
#pragma unroll
  for (int r = 0; r < TI; ++r) {
    Racc[r] = make_float4(0.f, 0.f, 0.f, 0.f);
    Sacc[r] = make_float4(0.f, 0.f, 0.f, 0.f);
  }
  float4 lacc = make_float4(0.f, 0.f, 0.f, 0.f);

  float4 kc0 = ((const float4*)(K + (j0 + f) * DIM))[dq];
  float4 kc1 = ((const float4*)(K + (j0 + 8 + f) * DIM))[dq];
  float4 vc0 = ((const float4*)(V + (j0 + f) * DIM))[dq];
  float4 vc1 = ((const float4*)(V + (j0 + 8 + f) * DIM))[dq];

  for (int sc = 0; sc < NSC; ++sc) {
    float4 pe0, pe1;
    pe0.x = epart(q4[0], kc0, wa4); pe0.y = epart(q4[1], kc0, wa4);
    pe0.z = epart(q4[2], kc0, wa4); pe0.w = epart(q4[3], kc0, wa4);
    pe1.x = epart(q4[0], kc1, wa4); pe1.y = epart(q4[1], kc1, wa4);
    pe1.z = epart(q4[2], kc1, wa4); pe1.w = epart(q4[3], kc1, wa4);

    const int scn = (sc + 1 < NSC) ? sc + 1 : sc;
    const int jb = j0 + scn * SC;
    const float4 kn0 = ((const float4*)(K + (jb + f) * DIM))[dq];
    const float4 kn1 = ((const float4*)(K + (jb + 8 + f) * DIM))[dq];
    const float4 vn0 = ((const float4*)(V + (jb + f) * DIM))[dq];
    const float4 vn1 = ((const float4*)(V + (jb + 8 + f) * DIM))[dq];

    pe0.x = red32(pe0.x); pe0.y = red32(pe0.y);
    pe0.z = red32(pe0.z); pe0.w = red32(pe0.w);
    pe1.x = red32(pe1.x); pe1.y = red32(pe1.y);
    pe1.z = red32(pe1.z); pe1.w = red32(pe1.w);

    float4 p0, p1;
    p0.x = __expf(bcast32(pe0.x, hi)); p0.y = __expf(bcast32(pe0.y, hi));
    p0.z = __expf(bcast32(pe0.z, hi)); p0.w = __expf(bcast32(pe0.w, hi));
    p1.x = __expf(bcast32(pe1.x, hi)); p1.y = __expf(bcast32(pe1.y, hi));
    p1.z = __expf(bcast32(pe1.z, hi)); p1.w = __expf(bcast32(pe1.w, hi));

    {
      const float pr0[4] = {p0.x, p0.y, p0.z, p0.w};
      const float pr1[4] = {p1.x, p1.y, p1.z, p1.w};
#pragma unroll
      for (int r = 0; r < TI; ++r) {
        const float pa = pr0[r], pb = pr1[r];
        Racc[r].x = fmaf(pa, fmaxf(q4[r].x + kc0.x, 0.f), Racc[r].x);
        Racc[r].y = fmaf(pa, fmaxf(q4[r].y + kc0.y, 0.f), Racc[r].y);
        Racc[r].z = fmaf(pa, fmaxf(q4[r].z + kc0.z, 0.f), Racc[r].z);
        Racc[r].w = fmaf(pa, fmaxf(q4[r].w + kc0.w, 0.f), Racc[r].w);
        Racc[r].x = fmaf(pb, fmaxf(q4[r].x + kc1.x, 0.f), Racc[r].x);
        Racc[r].y = fmaf(pb, fmaxf(q4[r].y + kc1.y, 0.f), Racc[r].y);
        Racc[r].z = fmaf(pb, fmaxf(q4[r].z + kc1.z, 0.f), Racc[r].z);
        Racc[r].w = fmaf(pb, fmaxf(q4[r].w + kc1.w, 0.f), Racc[r].w);
        Sacc[r].x = fmaf(pa, vc0.x, Sacc[r].x);
        Sacc[r].y = fmaf(pa, vc0.y, Sacc[r].y);
        Sacc[r].z = fmaf(pa, vc0.z, Sacc[r].z);
        Sacc[r].w = fmaf(pa, vc0.w, Sacc[r].w);
        Sacc[r].x = fmaf(pb, vc1.x, Sacc[r].x);
        Sacc[r].y = fmaf(pb, vc1.y, Sacc[r].y);
        Sacc[r].z = fmaf(pb, vc1.z, Sacc[r].z);
        Sacc[r].w = fmaf(pb, vc1.w, Sacc[r].w);
      }
      lacc.x += p0.x + p1.x; lacc.y += p0.y + p1.y;
      lacc.z += p0.z + p1.z; lacc.w += p0.w + p1.w;
    }

    kc0 = kn0; kc1 = kn1; vc0 = vn0; vc1 = vn1;
  }

  float4* F4 = (float4*)red_s;  // [f][r][dq]
#pragma unroll
  for (int r = 0; r < TI; ++r) F4[(f * 4 + r) * 32 + dq] = Racc[r];
  if (dq == 0) lred4[f] = lacc;
  __syncthreads();
#pragma unroll
  for (int p = 0; p < 2; ++p) {
    const int o = t + 256 * p;  // 0..511
    const int r = o >> 7, d = o & 127;
    float acc = 0.f;
#pragma unroll
    for (int c = 0; c < 8; ++c) acc += red_s[(c * 4 + r) * 128 + d];
    Rw[(jc * N + i0 + r) * DIM + d] = acc;
  }
  if (t < TI) {
    float l = 0.f;
#pragma unroll
    for (int c = 0; c < 8; ++c) l += ((const float*)&lred4[c])[t];
    Lw[jc * N + i0 + t] = l;
  }
  __syncthreads();
#pragma unroll
  for (int r = 0; r < TI; ++r) F4[(f * 4 + r) * 32 + dq] = Sacc[r];
  __syncthreads();
#pragma unroll
  for (int p = 0; p < 2; ++p) {
    const int o = t + 256 * p;
    const int r = o >> 7, d = o & 127;
    float acc = 0.f;
#pragma unroll
    for (int c = 0; c < 8; ++c) acc += red_s[(c * 4 + r) * 128 + d];
    Sw[(jc * N + i0 + r) * DIM + d] = acc;
  }
}

// ------------------------------------------------------------------
// Kernel 3 (round 8): combine, TWO rows per block (512 blocks).
//   - float4 WEv loads, dp-split-by-4 matvec, 4 KB LDS partials
//   - WEv L2 traffic halves (shared across 2 rows)
// ------------------------------------------------------------------
__global__ __launch_bounds__(256) void attn_combine3(
    const float* __restrict__ WEv, const float* __restrict__ bEv,
    const float* __restrict__ Rw, const float* __restrict__ Sw,
    const float* __restrict__ Lw, float* __restrict__ out) {
  const int i0 = blockIdx.x * 2;
  const int t = threadIdx.x;

  __shared__ __align__(16) float Rst[2][DIM];
  __shared__ __align__(16) float Sst[2][DIM];
  __shared__ __align__(16) float4 Eacc4[4][2][DIM / 4];  // 4 KB
  __shared__ float linv_s[2];

  // step 1: L per row (lanes 0..15 of wave 0: row = t>>3, chunk = t&7)
  if (t < 16) {
    const int row = t >> 3, c = t & 7;
    float l = Lw[c * N + i0 + row];
#pragma unroll
    for (int mask = 1; mask <= 4; mask <<= 1) l += __shfl_xor(l, mask, 8);
    if (c == 0) linv_s[row] = 1.0f / l;
  }

  // step 2: R*, S* (thread = (row, d); 8 coalesced scalar loads each)
  {
    const int row = t >> 7, d = t & 127;
    float r = 0.f, s = 0.f;
#pragma unroll
    for (int c = 0; c < 8; ++c) {
      r += Rw[(c * N + i0 + row) * DIM + d];
      s += Sw[(c * N + i0 + row) * DIM + d];
    }
    Rst[row][d] = r;
    Sst[row][d] = s;
  }
  __syncthreads();

  // step 3: matvec R* @ WEv, dp split by 4, float4 across d
  {
    const int dq = t & 31;          // output d-quad
    const int row = (t >> 5) & 1;   // row 0/1
    const int qr = t >> 6;          // dp-quarter 0..3
    const float4* WEv4 = (const float4*)WEv;
    float4 acc = make_float4(0.f, 0.f, 0.f, 0.f);
    const int dp0 = 32 * qr;
#pragma unroll 8
    for (int dp = dp0; dp < dp0 + 32; ++dp) {
      const float rv = Rst[row][dp];           // LDS broadcast
      const float4 w4 = WEv4[dp * 32 + dq];    // coalesced, shared by rows
      acc.x = fmaf(rv, w4.x, acc.x);
      acc.y = fmaf(rv, w4.y, acc.y);
      acc.z = fmaf(rv, w4.z, acc.z);
      acc.w = fmaf(rv, w4.w, acc.w);
    }
    Eacc4[qr][row][dq] = acc;
  }
  __syncthreads();

  // step 4: reduce quarters + normalize + bias + store (thread = (row,d))
  {
    const int row = t >> 7, d = t & 127;
    const int dq = d >> 2, e = d & 3;
    float acc = Sst[row][d];
#pragma unroll
    for (int qr = 0; qr < 4; ++qr)
      acc += ((const float*)&Eacc4[qr][row][dq])[e];
    out[(i0 + row) * DIM + d] = fmaf(acc, linv_s[row], bEv[d]);
  }
}

// ------------------------------------------------------------------
// Fallback (round-1 proven kernel) if ws is too small for partials.
// ------------------------------------------------------------------
__global__ __launch_bounds__(256) void attn_fallback(
    const float* __restrict__ Q, const float* __restrict__ K,
    const float* __restrict__ V, const float* __restrict__ WA,
    const float* __restrict__ WEv, const float* __restrict__ bEv,
    float* __restrict__ out) {
  const int i = blockIdx.x;
  const int t = threadIdx.x;

  __shared__ __align__(16) float qs[DIM];
  __shared__ __align__(16) float was[DIM];
  __shared__ __align__(16) float p[N];
  __shared__ float red[256];
  __shared__ __align__(16) float Rs[8][DIM];
  __shared__ __align__(16) float Ss[8][DIM];

  if (t < DIM) {
    qs[t] = Q[i * DIM + t];
    was[t] = WA[t];
  }
  __syncthreads();

  float evals[4];
  float mloc = -3.4e38f;
  for (int jj = 0; jj < 4; ++jj) {
    const int j = t + jj * 256;
    const float4* krow = (const float4*)(K + j * DIM);
    const float4* q4p = (const float4*)qs;
    const float4* w4p = (const float4*)was;
    float acc = 0.f;
    for (int d4 = 0; d4 < DIM / 4; ++d4) {
      const float4 k4 = krow[d4];
      const float4 q4 = q4p[d4];
      const float4 w4 = w4p[d4];
      acc = fmaf(fmaxf(q4.x + k4.x, 0.f), w4.x, acc);
      acc = fmaf(fmaxf(q4.y + k4.y, 0.f), w4.y, acc);
      acc = fmaf(fmaxf(q4.z + k4.z, 0.f), w4.z, acc);
      acc = fmaf(fmaxf(q4.w + k4.w, 0.f), w4.w, acc);
    }
    evals[jj] = acc;
    mloc = fmaxf(mloc, acc);
  }
  red[t] = mloc;
  __syncthreads();
  for (int s = 128; s > 0; s >>= 1) {
    if (t < s) red[t] = fmaxf(red[t], red[t + s]);
    __syncthreads();
  }
  const float m = red[0];
  __syncthreads();
  float lsum = 0.f;
  for (int jj = 0; jj < 4; ++jj) {
    const float pe = __expf(evals[jj] - m);
    p[t + jj * 256] = pe;
    lsum += pe;
  }
  red[t] = lsum;
  __syncthreads();
  for (int s = 128; s > 0; s >>= 1) {
    if (t < s) red[t] += red[t + s];
    __syncthreads();
  }
  const float linv = 1.0f / red[0];
  __syncthreads();

  const int tx = t & 31;
  const int ty = t >> 5;
  const float4 q4 = ((const float4*)qs)[tx];
  float4 R4 = make_float4(0.f, 0.f, 0.f, 0.f);
  float4 S4 = make_float4(0.f, 0.f, 0.f, 0.f);
  for (int j = ty; j < N; j += 8) {
    const float pj = p[j];
    const float4 k4 = ((const float4*)(K + j * DIM))[tx];
    const float4 v4 = ((const float4*)(V + j * DIM))[tx];
    R4.x = fmaf(pj, fmaxf(q4.x + k4.x, 0.f), R4.x);
    R4.y = fmaf(pj, fmaxf(q4.y + k4.y, 0.f), R4.y);
    R4.z = fmaf(pj, fmaxf(q4.z + k4.z, 0.f), R4.z);
    R4.w = fmaf(pj, fmaxf(q4.w + k4.w, 0.f), R4.w);
    S4.x = fmaf(pj, v4.x, S4.x);
    S4.y = fmaf(pj, v4.y, S4.y);
    S4.z = fmaf(pj, v4.z, S4.z);
    S4.w = fmaf(pj, v4.w, S4.w);
  }
  ((float4*)&Rs[ty][0])[tx] = R4;
  ((float4*)&Ss[ty][0])[tx] = S4;
  __syncthreads();

  if (t < DIM) {
    float R = 0.f, S = 0.f;
    for (int g = 0; g < 8; ++g) {
      R += Rs[g][t];
      S += Ss[g][t];
    }
    Rs[0][t] = R;
    Ss[0][t] = S;
  }
  __syncthreads();

  if (t < DIM) {
    float o = Ss[0][t];
    for (int dp = 0; dp < DIM; ++dp) {
      o = fmaf(Rs[0][dp], WEv[dp * DIM + t], o);
    }
    out[i * DIM + t] = fmaf(o, linv, bEv[t]);
  }
}

extern "C" void kernel_launch(void* const* d_in, const int* in_sizes, int n_in,
                              void* d_out, int out_size, void* d_ws, size_t ws_size,
                              hipStream_t stream) {
  const float* x    = (const float*)d_in[0];
  const float* W_Q  = (const float*)d_in[1];
  const float* b_Q  = (const float*)d_in[2];
  const float* W_K  = (const float*)d_in[3];
  const float* b_K  = (const float*)d_in[4];
  const float* W_V  = (const float*)d_in[5];
  const float* b_V  = (const float*)d_in[6];
  const float* W_Ev = (const float*)d_in[7];
  const float* b_Ev = (const float*)d_in[8];
  const float* W_A  = (const float*)d_in[9];
  // d_in[10] = b_A: constant shift under softmax — drops out exactly.

  float* Q = (float*)d_ws;            // N*DIM
  float* K = Q + N * DIM;             // N*DIM
  float* V = K + N * DIM;             // N*DIM
  float* out = (float*)d_out;

  const size_t need_floats = (size_t)3 * N * DIM + (size_t)2 * NCH * N * DIM +
                             (size_t)NCH * N;

  qkv_kernel2<<<N / 2, 256, 0, stream>>>(x, W_Q, b_Q, W_K, b_K, W_V, b_V, Q, K, V);

  if (ws_size >= need_floats * sizeof(float)) {
    float* Rw = V + N * DIM;            // NCH*N*DIM
    float* Sw = Rw + NCH * N * DIM;     // NCH*N*DIM
    float* Lw = Sw + NCH * N * DIM;     // NCH*N
    attn_fused4<<<(N / TI) * NCH, 256, 0, stream>>>(Q, K, V, W_A, Rw, Sw, Lw);
    attn_combine3<<<N / 2, 256, 0, stream>>>(W_Ev, b_Ev, Rw, Sw, Lw, out);
  } else {
    attn_fallback<<<N, 256, 0, stream>>>(Q, K, V, W_A, W_Ev, b_Ev, out);
  }
}

// Round 9
// 123.336 us; speedup vs baseline: 1.0524x; 1.0524x over previous
//
#include <hip/hip_runtime.h>

#define N 1024
#define DIM 128
#define TI 4      // rows per attn block
#define JCH 128   // j's per attn block
#define NCH 8     // number of j-chunks (N / JCH)
#define SC 16     // j sub-chunk per loop iter
#define NSC 8     // JCH / SC

// ---- DPP 32-lane sum (VALU pipe): group sums land in wave lanes 31 / 63 ----
template <int CTRL>
__device__ __forceinline__ float dpp_add(float x) {
  int y = __builtin_amdgcn_update_dpp(0, __float_as_int(x), CTRL, 0xF, 0xF, true);
  return x + __int_as_float(y);
}
__device__ __forceinline__ float red32(float x) {
  x = dpp_add<0x111>(x);  // row_shr:1
  x = dpp_add<0x112>(x);  // row_shr:2
  x = dpp_add<0x114>(x);  // row_shr:4
  x = dpp_add<0x118>(x);  // row_shr:8
  x = dpp_add<0x142>(x);  // row_bcast15 -> lanes 31/63 have their 32-lane sums
  return x;
}

// Broadcast the 32-lane group sum to every lane WITHOUT LDS.
__device__ __forceinline__ float bcast32(float x, bool hi) {
  const float a = __int_as_float(__builtin_amdgcn_readlane(__float_as_int(x), 31));
  const float b = __int_as_float(__builtin_amdgcn_readlane(__float_as_int(x), 63));
  return hi ? b : a;
}

__device__ __forceinline__ float epart(const float4 q, const float4 k,
                                       const float4 w) {
  float a = fmaxf(q.x + k.x, 0.f) * w.x;
  a = fmaf(fmaxf(q.y + k.y, 0.f), w.y, a);
  a = fmaf(fmaxf(q.z + k.z, 0.f), w.z, a);
  a = fmaf(fmaxf(q.w + k.w, 0.f), w.w, a);
  return a;
}

// ------------------------------------------------------------------
// Kernel 1: Q = x@W_Q+b_Q, K = x@W_K+b_K, V = x@W_V+b_V.  (r5-proven)
// ------------------------------------------------------------------
__global__ __launch_bounds__(256) void qkv_kernel2(
    const float* __restrict__ x,
    const float* __restrict__ WQ, const float* __restrict__ bQ,
    const float* __restrict__ WK, const float* __restrict__ bK,
    const float* __restrict__ WV, const float* __restrict__ bV,
    float* __restrict__ Q, float* __restrict__ K, float* __restrict__ V) {
  const int i0 = blockIdx.x * 2;
  const int t = threadIdx.x;
  const int dq = t & 31;
  const int g = t >> 5;
  const int r = g & 1;
  const int qr = g >> 1;

  __shared__ __align__(16) float xs[2][DIM];
  __shared__ __align__(16) float pacc[4][3][2][DIM];

  if (t < 64) {
    const int row = t >> 5, c4 = t & 31;
    ((float4*)&xs[row][0])[c4] = ((const float4*)(x + (i0 + row) * DIM))[c4];
  }
  __syncthreads();

  const float4* WQ4 = (const float4*)WQ;
  const float4* WK4 = (const float4*)WK;
  const float4* WV4 = (const float4*)WV;
  float4 aQ = make_float4(0.f, 0.f, 0.f, 0.f);
  float4 aK = make_float4(0.f, 0.f, 0.f, 0.f);
  float4 aV = make_float4(0.f, 0.f, 0.f, 0.f);
  const int cbase = 32 * qr;
  for (int cc = 0; cc < 32; ++cc) {
    const int c = cbase + cc;
    const float xv = xs[r][c];
    const float4 wq = WQ4[c * 32 + dq];
    const float4 wk = WK4[c * 32 + dq];
    const float4 wv = WV4[c * 32 + dq];
    aQ.x = fmaf(xv, wq.x, aQ.x); aQ.y = fmaf(xv, wq.y, aQ.y);
    aQ.z = fmaf(xv, wq.z, aQ.z); aQ.w = fmaf(xv, wq.w, aQ.w);
    aK.x = fmaf(xv, wk.x, aK.x); aK.y = fmaf(xv, wk.y, aK.y);
    aK.z = fmaf(xv, wk.z, aK.z); aK.w = fmaf(xv, wk.w, aK.w);
    aV.x = fmaf(xv, wv.x, aV.x); aV.y = fmaf(xv, wv.y, aV.y);
    aV.z = fmaf(xv, wv.z, aV.z); aV.w = fmaf(xv, wv.w, aV.w);
  }
  ((float4*)&pacc[qr][0][r][0])[dq] = aQ;
  ((float4*)&pacc[qr][1][r][0])[dq] = aK;
  ((float4*)&pacc[qr][2][r][0])[dq] = aV;
  __syncthreads();

  {
    const int row = t >> 7, d = t & 127;
    const float q = (pacc[0][0][row][d] + pacc[1][0][row][d]) +
                    (pacc[2][0][row][d] + pacc[3][0][row][d]) + bQ[d];
    const float k = (pacc[0][1][row][d] + pacc[1][1][row][d]) +
                    (pacc[2][1][row][d] + pacc[3][1][row][d]) + bK[d];
    const float v = (pacc[0][2][row][d] + pacc[1][2][row][d]) +
                    (pacc[2][2][row][d] + pacc[3][2][row][d]) + bV[d];
    Q[(i0 + row) * DIM + d] = q;
    K[(i0 + row) * DIM + d] = k;
    V[(i0 + row) * DIM + d] = v;
  }
}

// ------------------------------------------------------------------
// Kernel 2: barrier-free hot loop, zero LDS in the loop.  (r7-proven)
// ------------------------------------------------------------------
__global__ __launch_bounds__(256) void attn_fused4(
    const float* __restrict__ Q, const float* __restrict__ K,
    const float* __restrict__ V, const float* __restrict__ WA,
    float* __restrict__ Rw, float* __restrict__ Sw, float* __restrict__ Lw) {
  const int bi = blockIdx.x >> 3;
  const int jc = blockIdx.x & 7;
  const int i0 = bi * TI;
  const int j0 = jc * JCH;
  const int t = threadIdx.x;
  const int dq = t & 31;           // d-quad lane
  const int f = t >> 5;            // j-group 0..7
  const bool hi = (t & 32) != 0;   // which wave half this group occupies

  __shared__ __align__(16) float red_s[8 * TI * DIM];  // 16 KB epilogue buf
  __shared__ __align__(16) float4 lred4[8];

  const float4 wa4 = ((const float4*)WA)[dq];
  float4 q4[TI];
#pragma unroll
  for (int r = 0; r < TI; ++r)
    q4[r] = ((const float4*)(Q + (i0 + r) * DIM))[dq];

  float4 Racc[TI], Sacc[TI];
#pragma unroll
  for (int r = 0; r < TI; ++r) {
    Racc[r] = make_float4(0.f, 0.f, 0.f, 0.f);
    Sacc[r] = make_float4(0.f, 0.f, 0.f, 0.f);
  }
  float4 lacc = make_float4(0.f, 0.f, 0.f, 0.f);

  float4 kc0 = ((const float4*)(K + (j0 + f) * DIM))[dq];
  float4 kc1 = ((const float4*)(K + (j0 + 8 + f) * DIM))[dq];
  float4 vc0 = ((const float4*)(V + (j0 + f) * DIM))[dq];
  float4 vc1 = ((const float4*)(V + (j0 + 8 + f) * DIM))[dq];

  for (int sc = 0; sc < NSC; ++sc) {
    float4 pe0, pe1;
    pe0.x = epart(q4[0], kc0, wa4); pe0.y = epart(q4[1], kc0, wa4);
    pe0.z = epart(q4[2], kc0, wa4); pe0.w = epart(q4[3], kc0, wa4);
    pe1.x = epart(q4[0], kc1, wa4); pe1.y = epart(q4[1], kc1, wa4);
    pe1.z = epart(q4[2], kc1, wa4); pe1.w = epart(q4[3], kc1, wa4);

    const int scn = (sc + 1 < NSC) ? sc + 1 : sc;
    const int jb = j0 + scn * SC;
    const float4 kn0 = ((const float4*)(K + (jb + f) * DIM))[dq];
    const float4 kn1 = ((const float4*)(K + (jb + 8 + f) * DIM))[dq];
    const float4 vn0 = ((const float4*)(V + (jb + f) * DIM))[dq];
    const float4 vn1 = ((const float4*)(V + (jb + 8 + f) * DIM))[dq];

    pe0.x = red32(pe0.x); pe0.y = red32(pe0.y);
    pe0.z = red32(pe0.z); pe0.w = red32(pe0.w);
    pe1.x = red32(pe1.x); pe1.y = red32(pe1.y);
    pe1.z = red32(pe1.z); pe1.w = red32(pe1.w);

    float4 p0, p1;
    p0.x = __expf(bcast32(pe0.x, hi)); p0.y = __expf(bcast32(pe0.y, hi));
    p0.z = __expf(bcast32(pe0.z, hi)); p0.w = __expf(bcast32(pe0.w, hi));
    p1.x = __expf(bcast32(pe1.x, hi)); p1.y = __expf(bcast32(pe1.y, hi));
    p1.z = __expf(bcast32(pe1.z, hi)); p1.w = __expf(bcast32(pe1.w, hi));

    {
      const float pr0[4] = {p0.x, p0.y, p0.z, p0.w};
      const float pr1[4] = {p1.x, p1.y, p1.z, p1.w};
#pragma unroll
      for (int r = 0; r < TI; ++r) {
        const float pa = pr0[r], pb = pr1[r];
        Racc[r].x = fmaf(pa, fmaxf(q4[r].x + kc0.x, 0.f), Racc[r].x);
        Racc[r].y = fmaf(pa, fmaxf(q4[r].y + kc0.y, 0.f), Racc[r].y);
        Racc[r].z = fmaf(pa, fmaxf(q4[r].z + kc0.z, 0.f), Racc[r].z);
        Racc[r].w = fmaf(pa, fmaxf(q4[r].w + kc0.w, 0.f), Racc[r].w);
        Racc[r].x = fmaf(pb, fmaxf(q4[r].x + kc1.x, 0.f), Racc[r].x);
        Racc[r].y = fmaf(pb, fmaxf(q4[r].y + kc1.y, 0.f), Racc[r].y);
        Racc[r].z = fmaf(pb, fmaxf(q4[r].z + kc1.z, 0.f), Racc[r].z);
        Racc[r].w = fmaf(pb, fmaxf(q4[r].w + kc1.w, 0.f), Racc[r].w);
        Sacc[r].x = fmaf(pa, vc0.x, Sacc[r].x);
        Sacc[r].y = fmaf(pa, vc0.y, Sacc[r].y);
        Sacc[r].z = fmaf(pa, vc0.z, Sacc[r].z);
        Sacc[r].w = fmaf(pa, vc0.w, Sacc[r].w);
        Sacc[r].x = fmaf(pb, vc1.x, Sacc[r].x);
        Sacc[r].y = fmaf(pb, vc1.y, Sacc[r].y);
        Sacc[r].z = fmaf(pb, vc1.z, Sacc[r].z);
        Sacc[r].w = fmaf(pb, vc1.w, Sacc[r].w);
      }
      lacc.x += p0.x + p1.x; lacc.y += p0.y + p1.y;
      lacc.z += p0.z + p1.z; lacc.w += p0.w + p1.w;
    }

    kc0 = kn0; kc1 = kn1; vc0 = vn0; vc1 = vn1;
  }

  float4* F4 = (float4*)red_s;  // [f][r][dq]
#pragma unroll
  for (int r = 0; r < TI; ++r) F4[(f * 4 + r) * 32 + dq] = Racc[r];
  if (dq == 0) lred4[f] = lacc;
  __syncthreads();
#pragma unroll
  for (int p = 0; p < 2; ++p) {
    const int o = t + 256 * p;  // 0..511
    const int r = o >> 7, d = o & 127;
    float acc = 0.f;
#pragma unroll
    for (int c = 0; c < 8; ++c) acc += red_s[(c * 4 + r) * 128 + d];
    Rw[(jc * N + i0 + r) * DIM + d] = acc;
  }
  if (t < TI) {
    float l = 0.f;
#pragma unroll
    for (int c = 0; c < 8; ++c) l += ((const float*)&lred4[c])[t];
    Lw[jc * N + i0 + t] = l;
  }
  __syncthreads();
#pragma unroll
  for (int r = 0; r < TI; ++r) F4[(f * 4 + r) * 32 + dq] = Sacc[r];
  __syncthreads();
#pragma unroll
  for (int p = 0; p < 2; ++p) {
    const int o = t + 256 * p;
    const int r = o >> 7, d = o & 127;
    float acc = 0.f;
#pragma unroll
    for (int c = 0; c < 8; ++c) acc += red_s[(c * 4 + r) * 128 + d];
    Sw[(jc * N + i0 + r) * DIM + d] = acc;
  }
}

// ------------------------------------------------------------------
// Kernel 3 (round 9): combine, ONE row per block (1024 blocks — the
// r7-proven occupancy) with float4 WEv matvec (the good part of r8).
//   thread = (dq = output d-quad, qr = dp-eighth): 16 float4 FMA-loads.
// ------------------------------------------------------------------
__global__ __launch_bounds__(256) void attn_combine4(
    const float* __restrict__ WEv, const float* __restrict__ bEv,
    const float* __restrict__ Rw, const float* __restrict__ Sw,
    const float* __restrict__ Lw, float* __restrict__ out) {
  const int i = blockIdx.x;
  const int t = threadIdx.x;

  __shared__ __align__(16) float Rst[DIM];
  __shared__ __align__(16) float Sst[DIM];
  __shared__ __align__(16) float4 Eacc4[8][DIM / 4];  // 4 KB
  __shared__ float linv_s;

  // step 1: L (lanes 0..7 of wave 0)
  if (t < 8) {
    float l = Lw[t * N + i];
#pragma unroll
    for (int mask = 1; mask <= 4; mask <<= 1) l += __shfl_xor(l, mask, 8);
    if (t == 0) linv_s = 1.0f / l;
  }

  // step 2: R*, S* (half block each; coalesced over d)
  {
    const int d = t & 127, h = t >> 7;
    float acc = 0.f;
    if (h == 0) {
#pragma unroll
      for (int c = 0; c < 8; ++c) acc += Rw[(c * N + i) * DIM + d];
      Rst[d] = acc;
    } else {
#pragma unroll
      for (int c = 0; c < 8; ++c) acc += Sw[(c * N + i) * DIM + d];
      Sst[d] = acc;
    }
  }
  __syncthreads();

  // step 3: matvec R* @ WEv — dp split by 8, float4 across output d
  {
    const int dq = t & 31;   // output d-quad
    const int qr = t >> 5;   // dp-eighth 0..7
    const float4* WEv4 = (const float4*)WEv;
    float4 acc = make_float4(0.f, 0.f, 0.f, 0.f);
    const int dp0 = 16 * qr;
#pragma unroll 8
    for (int dp = dp0; dp < dp0 + 16; ++dp) {
      const float rv = Rst[dp];                // LDS broadcast
      const float4 w4 = WEv4[dp * 32 + dq];    // coalesced float4
      acc.x = fmaf(rv, w4.x, acc.x);
      acc.y = fmaf(rv, w4.y, acc.y);
      acc.z = fmaf(rv, w4.z, acc.z);
      acc.w = fmaf(rv, w4.w, acc.w);
    }
    Eacc4[qr][dq] = acc;
  }
  __syncthreads();

  // step 4: reduce eighths + normalize + bias + store
  if (t < DIM) {
    const int dq = t >> 2, e = t & 3;
    float acc = Sst[t];
#pragma unroll
    for (int qr = 0; qr < 8; ++qr)
      acc += ((const float*)&Eacc4[qr][dq])[e];
    out[i * DIM + t] = fmaf(acc, linv_s, bEv[t]);
  }
}

// ------------------------------------------------------------------
// Fallback (round-1 proven kernel) if ws is too small for partials.
// ------------------------------------------------------------------
__global__ __launch_bounds__(256) void attn_fallback(
    const float* __restrict__ Q, const float* __restrict__ K,
    const float* __restrict__ V, const float* __restrict__ WA,
    const float* __restrict__ WEv, const float* __restrict__ bEv,
    float* __restrict__ out) {
  const int i = blockIdx.x;
  const int t = threadIdx.x;

  __shared__ __align__(16) float qs[DIM];
  __shared__ __align__(16) float was[DIM];
  __shared__ __align__(16) float p[N];
  __shared__ float red[256];
  __shared__ __align__(16) float Rs[8][DIM];
  __shared__ __align__(16) float Ss[8][DIM];

  if (t < DIM) {
    qs[t] = Q[i * DIM + t];
    was[t] = WA[t];
  }
  __syncthreads();

  float evals[4];
  float mloc = -3.4e38f;
  for (int jj = 0; jj < 4; ++jj) {
    const int j = t + jj * 256;
    const float4* krow = (const float4*)(K + j * DIM);
    const float4* q4p = (const float4*)qs;
    const float4* w4p = (const float4*)was;
    float acc = 0.f;
    for (int d4 = 0; d4 < DIM / 4; ++d4) {
      const float4 k4 = krow[d4];
      const float4 q4 = q4p[d4];
      const float4 w4 = w4p[d4];
      acc = fmaf(fmaxf(q4.x + k4.x, 0.f), w4.x, acc);
      acc = fmaf(fmaxf(q4.y + k4.y, 0.f), w4.y, acc);
      acc = fmaf(fmaxf(q4.z + k4.z, 0.f), w4.z, acc);
      acc = fmaf(fmaxf(q4.w + k4.w, 0.f), w4.w, acc);
    }
    evals[jj] = acc;
    mloc = fmaxf(mloc, acc);
  }
  red[t] = mloc;
  __syncthreads();
  for (int s = 128; s > 0; s >>= 1) {
    if (t < s) red[t] = fmaxf(red[t], red[t + s]);
    __syncthreads();
  }
  const float m = red[0];
  __syncthreads();
  float lsum = 0.f;
  for (int jj = 0; jj < 4; ++jj) {
    const float pe = __expf(evals[jj] - m);
    p[t + jj * 256] = pe;
    lsum += pe;
  }
  red[t] = lsum;
  __syncthreads();
  for (int s = 128; s > 0; s >>= 1) {
    if (t < s) red[t] += red[t + s];
    __syncthreads();
  }
  const float linv = 1.0f / red[0];
  __syncthreads();

  const int tx = t & 31;
  const int ty = t >> 5;
  const float4 q4 = ((const float4*)qs)[tx];
  float4 R4 = make_float4(0.f, 0.f, 0.f, 0.f);
  float4 S4 = make_float4(0.f, 0.f, 0.f, 0.f);
  for (int j = ty; j < N; j += 8) {
    const float pj = p[j];
    const float4 k4 = ((const float4*)(K + j * DIM))[tx];
    const float4 v4 = ((const float4*)(V + j * DIM))[tx];
    R4.x = fmaf(pj, fmaxf(q4.x + k4.x, 0.f), R4.x);
    R4.y = fmaf(pj, fmaxf(q4.y + k4.y, 0.f), R4.y);
    R4.z = fmaf(pj, fmaxf(q4.z + k4.z, 0.f), R4.z);
    R4.w = fmaf(pj, fmaxf(q4.w + k4.w, 0.f), R4.w);
    S4.x = fmaf(pj, v4.x, S4.x);
    S4.y = fmaf(pj, v4.y, S4.y);
    S4.z = fmaf(pj, v4.z, S4.z);
    S4.w = fmaf(pj, v4.w, S4.w);
  }
  ((float4*)&Rs[ty][0])[tx] = R4;
  ((float4*)&Ss[ty][0])[tx] = S4;
  __syncthreads();

  if (t < DIM) {
    float R = 0.f, S = 0.f;
    for (int g = 0; g < 8; ++g) {
      R += Rs[g][t];
      S += Ss[g][t];
    }
    Rs[0][t] = R;
    Ss[0][t] = S;
  }
  __syncthreads();

  if (t < DIM) {
    float o = Ss[0][t];
    for (int dp = 0; dp < DIM; ++dp) {
      o = fmaf(Rs[0][dp], WEv[dp * DIM + t], o);
    }
    out[i * DIM + t] = fmaf(o, linv, bEv[t]);
  }
}

extern "C" void kernel_launch(void* const* d_in, const int* in_sizes, int n_in,
                              void* d_out, int out_size, void* d_ws, size_t ws_size,
                              hipStream_t stream) {
  const float* x    = (const float*)d_in[0];
  const float* W_Q  = (const float*)d_in[1];
  const float* b_Q  = (const float*)d_in[2];
  const float* W_K  = (const float*)d_in[3];
  const float* b_K  = (const float*)d_in[4];
  const float* W_V  = (const float*)d_in[5];
  const float* b_V  = (const float*)d_in[6];
  const float* W_Ev = (const float*)d_in[7];
  const float* b_Ev = (const float*)d_in[8];
  const float* W_A  = (const float*)d_in[9];
  // d_in[10] = b_A: constant shift under softmax — drops out exactly.

  float* Q = (float*)d_ws;            // N*DIM
  float* K = Q + N * DIM;             // N*DIM
  float* V = K + N * DIM;             // N*DIM
  float* out = (float*)d_out;

  const size_t need_floats = (size_t)3 * N * DIM + (size_t)2 * NCH * N * DIM +
                             (size_t)NCH * N;

  qkv_kernel2<<<N / 2, 256, 0, stream>>>(x, W_Q, b_Q, W_K, b_K, W_V, b_V, Q, K, V);

  if (ws_size >= need_floats * sizeof(float)) {
    float* Rw = V + N * DIM;            // NCH*N*DIM
    float* Sw = Rw + NCH * N * DIM;     // NCH*N*DIM
    float* Lw = Sw + NCH * N * DIM;     // NCH*N
    attn_fused4<<<(N / TI) * NCH, 256, 0, stream>>>(Q, K, V, W_A, Rw, Sw, Lw);
    attn_combine4<<<N, 256, 0, stream>>>(W_Ev, b_Ev, Rw, Sw, Lw, out);
  } else {
    attn_fallback<<<N, 256, 0, stream>>>(Q, K, V, W_A, W_Ev, b_Ev, out);
  }
}